// Round 9
// baseline (308.095 us; speedup 1.0000x reference)
//
#include <hip/hip_runtime.h>
#include <hip/hip_bf16.h>

#define D_MODEL 1024
#define BB 4
#define TT 2048
#define ROWS (BB*TT)     /* 8192 */
#define NCHUNK 128
#define CHLEN 16         /* NCHUNK*CHLEN == TT */

typedef __attribute__((ext_vector_type(8))) short short8;
typedef __attribute__((ext_vector_type(4))) float floatx4;

static __device__ __forceinline__ ushort f2bf(float f) {
    union { float f; unsigned u; } v; v.f = f;
    unsigned r = v.u + 0x7FFF + ((v.u >> 16) & 1);   // RNE
    return (ushort)(r >> 16);
}
static __device__ __forceinline__ float bf2f(ushort b) {
    union { unsigned u; float f; } v; v.u = ((unsigned)b) << 16;
    return v.f;
}

// async global->LDS, 16B per lane; LDS dest is wave-uniform base + lane*16
#define GLOAD_LDS16(gp, lp)                                                 \
    __builtin_amdgcn_global_load_lds(                                       \
        (const __attribute__((address_space(1))) void*)(gp),                \
        (__attribute__((address_space(3))) void*)(lp), 16, 0, 0)

// ---------------- fused prep ----------------
#define PREP_A 8192
#define PREP_B 4096
#define PREP_C 2048
__global__ __launch_bounds__(256) void prep_all(
    const float* __restrict__ x, ushort* __restrict__ xb,
    const float* __restrict__ W_in, ushort* __restrict__ WinT,
    const float* __restrict__ W_out, ushort* __restrict__ W1T,
    const float* __restrict__ lnw, const float* __restrict__ lnb,
    float* __restrict__ s1, float* __restrict__ c2,
    const float* __restrict__ nu_log, const float* __restrict__ theta_log,
    const float* __restrict__ gamma_log,
    float* __restrict__ fr, float* __restrict__ fi, float* __restrict__ gm) {
    __shared__ float smem[32 * 33 + 8 * 32 * 2];
    int bid = blockIdx.x, tid = threadIdx.x;
    if (bid < PREP_A) {
        int i = bid * 256 + tid;
        float4 v = ((const float4*)x)[i];
        ushort4 o;
        o.x = f2bf(v.x); o.y = f2bf(v.y); o.z = f2bf(v.z); o.w = f2bf(v.w);
        ((ushort4*)xb)[i] = o;
    } else if (bid < PREP_A + PREP_B) {
        int b2 = bid - PREP_A;                  // W_in: K=1024, N=4096
        int n0 = (b2 & 127) * 32, k0 = (b2 >> 7) * 32;
        int tx = tid & 31, ty = tid >> 5;
        float (*tile)[33] = (float (*)[33])smem;
#pragma unroll
        for (int j = 0; j < 4; ++j)
            tile[ty + j*8][tx] = W_in[(size_t)(k0 + ty + j*8) * 4096 + n0 + tx];
        __syncthreads();
#pragma unroll
        for (int j = 0; j < 4; ++j)
            WinT[(size_t)(n0 + ty + j*8) * 1024 + k0 + tx] = f2bf(tile[tx][ty + j*8]);
    } else if (bid < PREP_A + PREP_B + PREP_C) {
        int b2 = bid - PREP_A - PREP_B;         // W_out: K=2048, N=1024
        int n0 = (b2 & 31) * 32, k0 = (b2 >> 5) * 32;
        int tx = tid & 31, ty = tid >> 5;
        float (*tile)[33] = (float (*)[33])smem;
        float* red1 = smem + 32 * 33;
        float* red2 = red1 + 8 * 32;
        float p1 = 0.f, p2 = 0.f;              // col sums for n = n0+tx
#pragma unroll
        for (int j = 0; j < 4; ++j) {
            int k = k0 + ty + j * 8;
            float w = W_out[(size_t)k * 1024 + n0 + tx];
            float lw = lnw[k], lb = lnb[k];
            tile[ty + j*8][tx] = lw * w;
            p1 += lw * w; p2 += lb * w;
        }
        __syncthreads();
#pragma unroll
        for (int j = 0; j < 4; ++j)
            W1T[(size_t)(n0 + ty + j*8) * 2048 + k0 + tx] = f2bf(tile[tx][ty + j*8]);
        red1[ty * 32 + tx] = p1; red2[ty * 32 + tx] = p2;
        __syncthreads();
        if (ty == 0) {
            float a = 0.f, b = 0.f;
#pragma unroll
            for (int t = 0; t < 8; ++t) { a += red1[t * 32 + tx]; b += red2[t * 32 + tx]; }
            atomicAdd(&s1[n0 + tx], a);
            atomicAdd(&c2[n0 + tx], b);
        }
    } else {
        int c = (bid - PREP_A - PREP_B - PREP_C) * 256 + tid;
        if (c < D_MODEL) {
            float nu = expf(-expf(nu_log[c]));
            float th = expf(theta_log[c]);
            fr[c] = nu * cosf(th);
            fi[c] = nu * sinf(th);
            gm[c] = expf(gamma_log[c]);
        }
    }
}

#define P_PRE  do { __builtin_amdgcn_sched_barrier(0); __builtin_amdgcn_s_barrier();  \
                    asm volatile("s_waitcnt lgkmcnt(0)" ::: "memory");                \
                    __builtin_amdgcn_sched_barrier(0);                                \
                    __builtin_amdgcn_s_setprio(1); } while (0)
#define P_POST do { __builtin_amdgcn_s_setprio(0); __builtin_amdgcn_sched_barrier(0); \
                    __builtin_amdgcn_s_barrier();                                     \
                    __builtin_amdgcn_sched_barrier(0); } while (0)

// ------- GEMM1: 256x256-tile 8-phase bf16 MFMA (BK=64, counted vmcnt) ------
__global__ __launch_bounds__(512) void gemm256(
    const ushort* __restrict__ A, const ushort* __restrict__ B,
    int K, const float* __restrict__ bias,
    const float* __restrict__ gamma,
    ushort* __restrict__ out_r, ushort* __restrict__ out_i,
    ushort* __restrict__ out_o) {
    __shared__ ushort LA[2][256 * 64];   // 64 KiB
    __shared__ ushort LB[2][256 * 64];   // 64 KiB  (128 KiB total, 1 WG/CU)
    int tid = threadIdx.x;
    int lane = tid & 63;
    int wave = tid >> 6;
    int wp = wave >> 2;                  // 0..1
    int wq = wave & 3;                   // 0..3
    int lr = lane & 15, q = lane >> 4;
    int swl = lr & 7;
    int rs8 = tid >> 3, ch = tid & 7;    // staging: row-in-round, chunk
    int sw8 = (ch ^ (rs8 & 7)) * 8;      // pre-swizzled global k-offset

    int gx = gridDim.x;
    int nwg = gx * gridDim.y;
    int lid = blockIdx.y * gx + blockIdx.x;
    int per = nwg >> 3;
    int sid = (lid & 7) * per + (lid >> 3);
    long m0 = (long)(sid / gx) * 256;
    long n0 = (long)(sid % gx) * 256;
    const int NT = K >> 6;

    const ushort* Abase = A + (size_t)(m0 + rs8) * K + sw8;
    const ushort* Bbase = B + (size_t)(n0 + rs8) * K + sw8;

    floatx4 acc[8][4] = {};

#define STG_A(kt, P, R) GLOAD_LDS16(Abase + (size_t)(R) * K + (kt), \
                                    &LA[P][((R) + rs8) * 64 + ch * 8])
#define STG_B(kt, P, R) GLOAD_LDS16(Bbase + (size_t)(R) * K + (kt), \
                                    &LB[P][((R) + rs8) * 64 + ch * 8])

    // prologue: tile0 complete -> buf0; tile1 Ah0,Bh0,Bh1 -> buf1
    STG_A(0, 0, 0);    STG_A(0, 0, 64);
    STG_B(0, 0, 0);    STG_B(0, 0, 64);
    STG_B(0, 0, 128);  STG_B(0, 0, 192);
    STG_A(0, 0, 128);  STG_A(0, 0, 192);
    STG_A(64, 1, 0);   STG_A(64, 1, 64);
    STG_B(64, 1, 0);   STG_B(64, 1, 64);
    STG_B(64, 1, 128); STG_B(64, 1, 192);
    asm volatile("s_waitcnt vmcnt(6)" ::: "memory");
    __builtin_amdgcn_s_barrier();

    for (int t = 0; t < NT; ++t) {
        const int p = t & 1;
        int kt1 = (t + 1 < NT) ? (t + 1) << 6 : 0;
        int kt2 = (t + 2 < NT) ? (t + 2) << 6 : 0;
        short8 a[2][4], b0[2][2], b1[2][2];

        // ---- P1: quadrant (mh0,nh0); stage Ah1(t+1) -> buf p^1 ----
#pragma unroll
        for (int ks = 0; ks < 2; ++ks) {
#pragma unroll
            for (int r = 0; r < 4; ++r)
                a[ks][r] = *(const short8*)&LA[p][(wp * 64 + r * 16 + lr) * 64 + ((ks * 4 + q) ^ swl) * 8];
#pragma unroll
            for (int c = 0; c < 2; ++c)
                b0[ks][c] = *(const short8*)&LB[p][(wq * 32 + c * 16 + lr) * 64 + ((ks * 4 + q) ^ swl) * 8];
        }
        STG_A(kt1, p ^ 1, 128); STG_A(kt1, p ^ 1, 192);
        P_PRE;
#pragma unroll
        for (int ks = 0; ks < 2; ++ks)
#pragma unroll
            for (int r = 0; r < 4; ++r)
#pragma unroll
                for (int c = 0; c < 2; ++c)
                    acc[r][c] = __builtin_amdgcn_mfma_f32_16x16x32_bf16(
                        a[ks][r], b0[ks][c], acc[r][c], 0, 0, 0);
        P_POST;

        // ---- P2: quadrant (mh0,nh1); stage Ah0(t+2) -> buf p ----
#pragma unroll
        for (int ks = 0; ks < 2; ++ks)
#pragma unroll
            for (int c = 0; c < 2; ++c)
                b1[ks][c] = *(const short8*)&LB[p][(128 + wq * 32 + c * 16 + lr) * 64 + ((ks * 4 + q) ^ swl) * 8];
        STG_A(kt2, p, 0); STG_A(kt2, p, 64);
        P_PRE;
#pragma unroll
        for (int ks = 0; ks < 2; ++ks)
#pragma unroll
            for (int r = 0; r < 4; ++r)
#pragma unroll
                for (int c = 0; c < 2; ++c)
                    acc[r][2 + c] = __builtin_amdgcn_mfma_f32_16x16x32_bf16(
                        a[ks][r], b1[ks][c], acc[r][2 + c], 0, 0, 0);
        P_POST;

        // ---- P3: quadrant (mh1,nh0); stage Bh0(t+2) -> buf p ----
#pragma unroll
        for (int ks = 0; ks < 2; ++ks)
#pragma unroll
            for (int r = 0; r < 4; ++r)
                a[ks][r] = *(const short8*)&LA[p][(128 + wp * 64 + r * 16 + lr) * 64 + ((ks * 4 + q) ^ swl) * 8];
        STG_B(kt2, p, 0); STG_B(kt2, p, 64);
        P_PRE;
#pragma unroll
        for (int ks = 0; ks < 2; ++ks)
#pragma unroll
            for (int r = 0; r < 4; ++r)
#pragma unroll
                for (int c = 0; c < 2; ++c)
                    acc[4 + r][c] = __builtin_amdgcn_mfma_f32_16x16x32_bf16(
                        a[ks][r], b0[ks][c], acc[4 + r][c], 0, 0, 0);
        P_POST;

        // ---- P4: quadrant (mh1,nh1); stage Bh1(t+2) -> buf p; vmcnt(6) ----
        STG_B(kt2, p, 128); STG_B(kt2, p, 192);
        asm volatile("s_waitcnt vmcnt(6)" ::: "memory");
        P_PRE;
#pragma unroll
        for (int ks = 0; ks < 2; ++ks)
#pragma unroll
            for (int r = 0; r < 4; ++r)
#pragma unroll
                for (int c = 0; c < 2; ++c)
                    acc[4 + r][2 + c] = __builtin_amdgcn_mfma_f32_16x16x32_bf16(
                        a[ks][r], b1[ks][c], acc[4 + r][2 + c], 0, 0, 0);
        P_POST;
    }
    asm volatile("s_waitcnt vmcnt(0)" ::: "memory");

    int sector = (int)(n0 >> 10);                // block-uniform (BN=256)
    if (sector < 2) {
        ushort* dst = sector ? out_i : out_r;
#pragma unroll
        for (int nh = 0; nh < 2; ++nh)
#pragma unroll
            for (int c = 0; c < 2; ++c) {
                int lc = (int)(n0 & 1023) + nh * 128 + wq * 32 + c * 16 + lr;
                float bv = bias[(sector << 10) + lc];
                float gv = gamma[lc];
#pragma unroll
                for (int mh = 0; mh < 2; ++mh)
#pragma unroll
                    for (int r = 0; r < 4; ++r)
#pragma unroll
                        for (int g = 0; g < 4; ++g) {
                            long row = m0 + mh * 128 + wp * 64 + r * 16 + q * 4 + g;
                            dst[row * 1024 + lc] = f2bf(gv * (acc[mh * 4 + r][nh * 2 + c][g] + bv));
                        }
            }
    } else {
        int oc0 = (int)(n0 - 2048);
#pragma unroll
        for (int nh = 0; nh < 2; ++nh)
#pragma unroll
            for (int c = 0; c < 2; ++c) {
                int oc = oc0 + nh * 128 + wq * 32 + c * 16 + lr;
                float bv = bias[2048 + oc];
#pragma unroll
                for (int mh = 0; mh < 2; ++mh)
#pragma unroll
                    for (int r = 0; r < 4; ++r)
#pragma unroll
                        for (int g = 0; g < 4; ++g) {
                            long row = m0 + mh * 128 + wp * 64 + r * 16 + q * 4 + g;
                            out_o[row * 2048 + oc] = f2bf(acc[mh * 4 + r][nh * 2 + c][g] + bv);
                        }
            }
    }
#undef STG_A
#undef STG_B
}

// ------- GEMM2: 128x256-tile 8-phase (BK=64, counted vmcnt(3)) -------------
// R4-verified kernel, unchanged.
__global__ __launch_bounds__(512) void gemm2_8ph(
    const ushort* __restrict__ A, const ushort* __restrict__ B,
    int K, int N, const float* __restrict__ bias, float* __restrict__ outC,
    const float* __restrict__ mu, const float* __restrict__ rs,
    const float* __restrict__ s1, const float* __restrict__ c2) {
    __shared__ ushort LA[2][128 * 64];   // 32 KiB
    __shared__ ushort LB[2][256 * 64];   // 64 KiB  (96 KiB total, 1 WG/CU)
    int tid = threadIdx.x;
    int lane = tid & 63;
    int wave = tid >> 6;
    int wp = wave >> 2;                  // 0..1 (M)
    int wq = wave & 3;                   // 0..3 (N)
    int lr = lane & 15, q = lane >> 4;
    int swl = lr & 7;
    int rs8 = tid >> 3, ch = tid & 7;
    int sw8 = (ch ^ (rs8 & 7)) * 8;

    int gx = gridDim.x;                  // 4
    int nwg = gx * gridDim.y;            // 256
    int lid = blockIdx.y * gx + blockIdx.x;
    int per = nwg >> 3;
    int sid = (lid & 7) * per + (lid >> 3);
    long m0 = (long)(sid / gx) * 128;
    long n0 = (long)(sid % gx) * 256;
    const int NT = K >> 6;

    const ushort* Abase = A + (size_t)(m0 + rs8) * K + sw8;
    const ushort* Bbase = B + (size_t)(n0 + rs8) * K + sw8;

    floatx4 acc[4][4] = {};              // [mh*2+r][nh*2+c]

#define STG2_A(kt, P, R) GLOAD_LDS16(Abase + (size_t)(R) * K + (kt), \
                                     &LA[P][((R) + rs8) * 64 + ch * 8])
#define STG2_B(kt, P, R) GLOAD_LDS16(Bbase + (size_t)(R) * K + (kt), \
                                     &LB[P][((R) + rs8) * 64 + ch * 8])

    // prologue: tile0 full (6 loads) -> buf0; tile1 Ah0 + Bh0 -> buf1
    STG2_A(0, 0, 0);   STG2_A(0, 0, 64);
    STG2_B(0, 0, 0);   STG2_B(0, 0, 64);
    STG2_B(0, 0, 128); STG2_B(0, 0, 192);
    STG2_A(64, 1, 0);
    STG2_B(64, 1, 0);  STG2_B(64, 1, 64);
    asm volatile("s_waitcnt vmcnt(3)" ::: "memory");
    __builtin_amdgcn_s_barrier();

    for (int t = 0; t < NT; ++t) {
        const int p = t & 1;
        int kt1 = (t + 1 < NT) ? (t + 1) << 6 : 0;
        int kt2 = (t + 2 < NT) ? (t + 2) << 6 : 0;
        short8 a[2][2], b0[2][2], b1[2][2];

        // ---- P1 (mh0,nh0): read a(mh0) + b0; stage Ah1(t+1), Bh1(t+1) ----
#pragma unroll
        for (int ks = 0; ks < 2; ++ks) {
#pragma unroll
            for (int r = 0; r < 2; ++r)
                a[ks][r] = *(const short8*)&LA[p][(wp * 32 + r * 16 + lr) * 64 + ((ks * 4 + q) ^ swl) * 8];
#pragma unroll
            for (int c = 0; c < 2; ++c)
                b0[ks][c] = *(const short8*)&LB[p][(wq * 32 + c * 16 + lr) * 64 + ((ks * 4 + q) ^ swl) * 8];
        }
        STG2_A(kt1, p ^ 1, 64);
        STG2_B(kt1, p ^ 1, 128); STG2_B(kt1, p ^ 1, 192);
        P_PRE;
#pragma unroll
        for (int ks = 0; ks < 2; ++ks)
#pragma unroll
            for (int r = 0; r < 2; ++r)
#pragma unroll
                for (int c = 0; c < 2; ++c)
                    acc[r][c] = __builtin_amdgcn_mfma_f32_16x16x32_bf16(
                        a[ks][r], b0[ks][c], acc[r][c], 0, 0, 0);
        P_POST;

        // ---- P2 (mh0,nh1): read b1 ----
#pragma unroll
        for (int ks = 0; ks < 2; ++ks)
#pragma unroll
            for (int c = 0; c < 2; ++c)
                b1[ks][c] = *(const short8*)&LB[p][(128 + wq * 32 + c * 16 + lr) * 64 + ((ks * 4 + q) ^ swl) * 8];
        P_PRE;
#pragma unroll
        for (int ks = 0; ks < 2; ++ks)
#pragma unroll
            for (int r = 0; r < 2; ++r)
#pragma unroll
                for (int c = 0; c < 2; ++c)
                    acc[r][2 + c] = __builtin_amdgcn_mfma_f32_16x16x32_bf16(
                        a[ks][r], b1[ks][c], acc[r][2 + c], 0, 0, 0);
        P_POST;

        // ---- P3 (mh1,nh0): read a(mh1); stage Ah0(t+2) -> buf p ----
#pragma unroll
        for (int ks = 0; ks < 2; ++ks)
#pragma unroll
            for (int r = 0; r < 2; ++r)
                a[ks][r] = *(const short8*)&LA[p][(64 + wp * 32 + r * 16 + lr) * 64 + ((ks * 4 + q) ^ swl) * 8];
        STG2_A(kt2, p, 0);
        P_PRE;
#pragma unroll
        for (int ks = 0; ks < 2; ++ks)
#pragma unroll
            for (int r = 0; r < 2; ++r)
#pragma unroll
                for (int c = 0; c < 2; ++c)
                    acc[2 + r][c] = __builtin_amdgcn_mfma_f32_16x16x32_bf16(
                        a[ks][r], b0[ks][c], acc[2 + r][c], 0, 0, 0);
        P_POST;

        // ---- P4 (mh1,nh1): stage Bh0(t+2) -> buf p; vmcnt(3) ----
        STG2_B(kt2, p, 0); STG2_B(kt2, p, 64);
        asm volatile("s_waitcnt vmcnt(3)" ::: "memory");
        P_PRE;
#pragma unroll
        for (int ks = 0; ks < 2; ++ks)
#pragma unroll
            for (int r = 0; r < 2; ++r)
#pragma unroll
                for (int c = 0; c < 2; ++c)
                    acc[2 + r][2 + c] = __builtin_amdgcn_mfma_f32_16x16x32_bf16(
                        a[ks][r], b1[ks][c], acc[2 + r][2 + c], 0, 0, 0);
        P_POST;
    }
    asm volatile("s_waitcnt vmcnt(0)" ::: "memory");

    // LN-folded epilogue
#pragma unroll
    for (int nh = 0; nh < 2; ++nh)
#pragma unroll
        for (int c = 0; c < 2; ++c) {
            long col = n0 + nh * 128 + wq * 32 + c * 16 + lr;
            float bc = c2[col] + bias[col];
            float s1c = s1[col];
#pragma unroll
            for (int mh = 0; mh < 2; ++mh)
#pragma unroll
                for (int r = 0; r < 2; ++r)
#pragma unroll
                    for (int g = 0; g < 4; ++g) {
                        long row = m0 + mh * 64 + wp * 32 + r * 16 + q * 4 + g;
                        outC[row * (long)N + col] =
                            rs[row] * (acc[mh * 2 + r][nh * 2 + c][g] - mu[row] * s1c) + bc;
                    }
        }
#undef STG2_A
#undef STG2_B
}

// ------- chunked complex scan: 4 channels/thread, 8B uint2 loads (G13) -----
// CHLEN=16, NCHUNK=128 -> 512 blocks (2/CU); 16-step chains w/ 4-way ILP.
// carry layout: [b][ck][cq][8 floats] = {h0r,h0i,h1r,h1i, h2r,h2i,h3r,h3i}
__global__ __launch_bounds__(256) void scan_carries(
    const ushort* __restrict__ in_r, const ushort* __restrict__ in_i,
    float* __restrict__ carry,
    const float* __restrict__ fr_, const float* __restrict__ fi_) {
    int t = blockIdx.x * 256 + threadIdx.x;  // BB*256*NCHUNK = 131072
    int cq = t & 255;                        // channel-quad
    int ck = (t >> 8) & (NCHUNK - 1);
    int b = t >> 15;
    int c0 = cq * 4;
    float f_r[4], f_i[4], h_r[4] = {}, h_i[4] = {};
#pragma unroll
    for (int k = 0; k < 4; ++k) { f_r[k] = fr_[c0 + k]; f_i[k] = fi_[c0 + k]; }
    size_t base = ((size_t)(b * TT + ck * CHLEN)) * 1024 + c0;
#pragma unroll 4
    for (int j = 0; j < CHLEN; ++j) {
        uint2 ur = *(const uint2*)(in_r + base + (size_t)j * 1024);
        uint2 ui = *(const uint2*)(in_i + base + (size_t)j * 1024);
        uint wr[2] = {ur.x, ur.y}, wi[2] = {ui.x, ui.y};
#pragma unroll
        for (int k = 0; k < 4; ++k) {
            float r = bf2f((ushort)(wr[k >> 1] >> ((k & 1) * 16)));
            float im = bf2f((ushort)(wi[k >> 1] >> ((k & 1) * 16)));
            float nr = f_r[k] * h_r[k] - f_i[k] * h_i[k] + r;
            float ni = f_r[k] * h_i[k] + f_i[k] * h_r[k] + im;
            h_r[k] = nr; h_i[k] = ni;
        }
    }
    float4* cw = (float4*)(carry + (((size_t)b * NCHUNK + ck) * 256 + cq) * 8);
    cw[0] = make_float4(h_r[0], h_i[0], h_r[1], h_i[1]);
    cw[1] = make_float4(h_r[2], h_i[2], h_r[3], h_i[3]);
}

// middle: sequential prefix over NCHUNK carries, converts to carry-INs.
__global__ __launch_bounds__(256) void carry_prefix(
    float* __restrict__ carry,
    const float* __restrict__ fr_, const float* __restrict__ fi_) {
    int t = blockIdx.x * 256 + threadIdx.x;   // BB*256 = 1024
    int cq = t & 255, b = t >> 8;
    int c0 = cq * 4;
    float a_r[4], a_i[4], C_r[4] = {}, C_i[4] = {};
#pragma unroll
    for (int k = 0; k < 4; ++k) { a_r[k] = fr_[c0 + k]; a_i[k] = fi_[c0 + k]; }
#pragma unroll
    for (int s = 0; s < 4; ++s) {            // f^16 (CHLEN=16=2^4)
#pragma unroll
        for (int k = 0; k < 4; ++k) {
            float nr = a_r[k] * a_r[k] - a_i[k] * a_i[k];
            float ni = 2.f * a_r[k] * a_i[k];
            a_r[k] = nr; a_i[k] = ni;
        }
    }
    float* base = carry + ((size_t)b * NCHUNK * 256 + cq) * 8;
    for (int ckk = 0; ckk < NCHUNK; ++ckk) {
        float4* p = (float4*)(base + (size_t)ckk * 256 * 8);
        float4 s0 = p[0], s1v = p[1];
        p[0] = make_float4(C_r[0], C_i[0], C_r[1], C_i[1]);
        p[1] = make_float4(C_r[2], C_i[2], C_r[3], C_i[3]);
        float sr[4] = {s0.x, s0.z, s1v.x, s1v.z};
        float si[4] = {s0.y, s0.w, s1v.y, s1v.w};
#pragma unroll
        for (int k = 0; k < 4; ++k) {
            float nr = a_r[k] * C_r[k] - a_i[k] * C_i[k] + sr[k];
            float ni = a_r[k] * C_i[k] + a_i[k] * C_r[k] + si[k];
            C_r[k] = nr; C_i[k] = ni;
        }
    }
}

// pass B: load carry-in (32B), rescan chunk, emit y' = h*silu(o).
__global__ __launch_bounds__(256) void scan_apply(
    const ushort* __restrict__ in_r, const ushort* __restrict__ in_i,
    const float* __restrict__ carry,
    const float* __restrict__ fr_, const float* __restrict__ fi_,
    const ushort* __restrict__ o, ushort* __restrict__ yb) {
    int t = blockIdx.x * 256 + threadIdx.x;  // 131072
    int cq = t & 255;
    int ck = (t >> 8) & (NCHUNK - 1);
    int b = t >> 15;
    int c0 = cq * 4;
    float f_r[4], f_i[4], h_r[4], h_i[4];
#pragma unroll
    for (int k = 0; k < 4; ++k) { f_r[k] = fr_[c0 + k]; f_i[k] = fi_[c0 + k]; }
    const float4* cr = (const float4*)(carry + (((size_t)b * NCHUNK + ck) * 256 + cq) * 8);
    float4 C0 = cr[0], C1 = cr[1];
    h_r[0] = C0.x; h_i[0] = C0.y; h_r[1] = C0.z; h_i[1] = C0.w;
    h_r[2] = C1.x; h_i[2] = C1.y; h_r[3] = C1.z; h_i[3] = C1.w;
    size_t base = ((size_t)(b * TT + ck * CHLEN)) * 1024 + c0;
    size_t rowbase = (size_t)(b * TT + ck * CHLEN);
#pragma unroll 4
    for (int j = 0; j < CHLEN; ++j) {
        uint2 ur = *(const uint2*)(in_r + base + (size_t)j * 1024);
        uint2 ui = *(const uint2*)(in_i + base + (size_t)j * 1024);
        size_t ob = (rowbase + j) * 2048 + c0;
        uint2 uo1 = *(const uint2*)(o + ob);          // gate, first-half chans
        uint2 uo2 = *(const uint2*)(o + ob + 1024);   // gate, second-half
        uint wr[2] = {ur.x, ur.y}, wi[2] = {ui.x, ui.y};
        uint w1[2] = {uo1.x, uo1.y}, w2[2] = {uo2.x, uo2.y};
        uint y1[2], y2[2];
#pragma unroll
        for (int k = 0; k < 4; ++k) {
            float r = bf2f((ushort)(wr[k >> 1] >> ((k & 1) * 16)));
            float im = bf2f((ushort)(wi[k >> 1] >> ((k & 1) * 16)));
            float nr = f_r[k] * h_r[k] - f_i[k] * h_i[k] + r;
            float ni = f_r[k] * h_i[k] + f_i[k] * h_r[k] + im;
            h_r[k] = nr; h_i[k] = ni;
            float o1 = bf2f((ushort)(w1[k >> 1] >> ((k & 1) * 16)));
            float o2 = bf2f((ushort)(w2[k >> 1] >> ((k & 1) * 16)));
            float ya = h_r[k] * o1 / (1.f + __expf(-o1));
            float ybv = h_i[k] * o2 / (1.f + __expf(-o2));
            ushort pa = f2bf(ya), pb = f2bf(ybv);
            if (k & 1) { y1[k >> 1] |= (uint)pa << 16; y2[k >> 1] |= (uint)pb << 16; }
            else       { y1[k >> 1] = pa;              y2[k >> 1] = pb; }
        }
        *(uint2*)(yb + ob) = make_uint2(y1[0], y1[1]);
        *(uint2*)(yb + ob + 1024) = make_uint2(y2[0], y2[1]);
    }
}

// ---------------- per-row stats of y': one WAVE per row ----------------
__global__ __launch_bounds__(256) void row_stats(
    const ushort* __restrict__ yb, float* __restrict__ mu_o,
    float* __restrict__ rs_o) {
    int tid = threadIdx.x;
    long row = (long)blockIdx.x * 4 + (tid >> 6);
    int lane = tid & 63;
    const ushort* p = yb + row * 2048 + lane * 32;
    float s = 0.f, s2 = 0.f;
#pragma unroll
    for (int j = 0; j < 4; ++j) {
        uint4 raw = *(const uint4*)(p + j * 8);
        unsigned w[4] = {raw.x, raw.y, raw.z, raw.w};
#pragma unroll
        for (int e = 0; e < 4; ++e) {
            float a = bf2f((ushort)(w[e] & 0xffff));
            float bq = bf2f((ushort)(w[e] >> 16));
            s += a + bq; s2 += a * a + bq * bq;
        }
    }
#pragma unroll
    for (int off = 32; off > 0; off >>= 1) {
        s += __shfl_down(s, off, 64);
        s2 += __shfl_down(s2, off, 64);
    }
    if (lane == 0) {
        float mu = s * (1.f / 2048.f);
        float var = s2 * (1.f / 2048.f) - mu * mu;
        mu_o[row] = mu;
        rs_o[row] = rsqrtf(var + 1e-5f);
    }
}

// ---------------- launch ----------------

extern "C" void kernel_launch(void* const* d_in, const int* in_sizes, int n_in,
                              void* d_out, int out_size, void* d_ws, size_t ws_size,
                              hipStream_t stream) {
    const float* x         = (const float*)d_in[0];
    const float* W_in      = (const float*)d_in[1];
    const float* b_in      = (const float*)d_in[2];
    const float* nu_log    = (const float*)d_in[3];
    const float* theta_log = (const float*)d_in[4];
    const float* gamma_log = (const float*)d_in[5];
    const float* ln_w      = (const float*)d_in[6];
    const float* ln_b      = (const float*)d_in[7];
    const float* W_out     = (const float*)d_in[8];
    const float* b_out     = (const float*)d_in[9];
    float* out = (float*)d_out;

    char* ws = (char*)d_ws;
    size_t off = 0;
    auto alloc = [&](size_t bytes) {
        char* p = ws + off;
        off += (bytes + 255) & ~(size_t)255;
        return p;
    };
    ushort* xb    = (ushort*)alloc((size_t)ROWS * 1024 * 2);
    ushort* WinT  = (ushort*)alloc((size_t)4096 * 1024 * 2);
    ushort* W1T   = (ushort*)alloc((size_t)1024 * 2048 * 2);
    float*  fr    = (float*)alloc(1024 * 4);
    float*  fi    = (float*)alloc(1024 * 4);
    float*  gm    = (float*)alloc(1024 * 4);
    float*  s1c2  = (float*)alloc(2048 * 4);           // s1 | c2
    float*  s1    = s1c2;
    float*  c2    = s1c2 + 1024;
    ushort* in_r  = (ushort*)alloc((size_t)ROWS * 1024 * 2);
    ushort* in_i  = (ushort*)alloc((size_t)ROWS * 1024 * 2);
    ushort* obuf  = (ushort*)alloc((size_t)ROWS * 2048 * 2);
    float*  carry = (float*)alloc((size_t)BB * NCHUNK * 256 * 8 * 4);
    ushort* yb    = (ushort*)alloc((size_t)ROWS * 2048 * 2);
    float*  muv   = (float*)alloc(ROWS * 4);
    float*  rsv   = (float*)alloc(ROWS * 4);

    hipMemsetAsync(s1c2, 0, 2048 * 4, stream);

    prep_all<<<PREP_A + PREP_B + PREP_C + 4, 256, 0, stream>>>(
        x, xb, W_in, WinT, W_out, W1T, ln_w, ln_b, s1, c2,
        nu_log, theta_log, gamma_log, fr, fi, gm);

    gemm256<<<dim3(4096 / 256, ROWS / 256), 512, 0, stream>>>(
        xb, WinT, 1024, b_in, gm, in_r, in_i, obuf);

    scan_carries<<<BB * 256 * NCHUNK / 256, 256, 0, stream>>>(in_r, in_i, carry, fr, fi);
    carry_prefix<<<BB * 256 / 256, 256, 0, stream>>>(carry, fr, fi);
    scan_apply<<<BB * 256 * NCHUNK / 256, 256, 0, stream>>>(
        in_r, in_i, carry, fr, fi, obuf, yb);

    row_stats<<<ROWS / 4, 256, 0, stream>>>(yb, muv, rsv);

    gemm2_8ph<<<dim3(1024 / 256, ROWS / 128), 512, 0, stream>>>(
        yb, W1T, 2048, 1024, b_out, out, muv, rsv, s1, c2);
}

// Round 10
// 273.291 us; speedup vs baseline: 1.1274x; 1.1274x over previous
//
#include <hip/hip_runtime.h>
#include <hip/hip_bf16.h>

#define D_MODEL 1024
#define BB 4
#define TT 2048
#define ROWS (BB*TT)     /* 8192 */
#define NCHUNK 64
#define CHLEN 32         /* NCHUNK*CHLEN == TT */

typedef __attribute__((ext_vector_type(8))) short short8;
typedef __attribute__((ext_vector_type(4))) float floatx4;

static __device__ __forceinline__ ushort f2bf(float f) {
    union { float f; unsigned u; } v; v.f = f;
    unsigned r = v.u + 0x7FFF + ((v.u >> 16) & 1);   // RNE
    return (ushort)(r >> 16);
}
static __device__ __forceinline__ float bf2f(ushort b) {
    union { unsigned u; float f; } v; v.u = ((unsigned)b) << 16;
    return v.f;
}

// async global->LDS, 16B per lane; LDS dest is wave-uniform base + lane*16
#define GLOAD_LDS16(gp, lp)                                                 \
    __builtin_amdgcn_global_load_lds(                                       \
        (const __attribute__((address_space(1))) void*)(gp),                \
        (__attribute__((address_space(3))) void*)(lp), 16, 0, 0)

// ---------------- fused prep ----------------
#define PREP_A 8192
#define PREP_B 4096
#define PREP_C 2048
__global__ __launch_bounds__(256) void prep_all(
    const float* __restrict__ x, ushort* __restrict__ xb,
    const float* __restrict__ W_in, ushort* __restrict__ WinT,
    const float* __restrict__ W_out, ushort* __restrict__ W1T,
    const float* __restrict__ lnw, const float* __restrict__ lnb,
    float* __restrict__ s1, float* __restrict__ c2,
    const float* __restrict__ nu_log, const float* __restrict__ theta_log,
    const float* __restrict__ gamma_log,
    float* __restrict__ fr, float* __restrict__ fi, float* __restrict__ gm) {
    __shared__ float smem[32 * 33 + 8 * 32 * 2];
    int bid = blockIdx.x, tid = threadIdx.x;
    if (bid < PREP_A) {
        int i = bid * 256 + tid;
        float4 v = ((const float4*)x)[i];
        ushort4 o;
        o.x = f2bf(v.x); o.y = f2bf(v.y); o.z = f2bf(v.z); o.w = f2bf(v.w);
        ((ushort4*)xb)[i] = o;
    } else if (bid < PREP_A + PREP_B) {
        int b2 = bid - PREP_A;                  // W_in: K=1024, N=4096
        int n0 = (b2 & 127) * 32, k0 = (b2 >> 7) * 32;
        int tx = tid & 31, ty = tid >> 5;
        float (*tile)[33] = (float (*)[33])smem;
#pragma unroll
        for (int j = 0; j < 4; ++j)
            tile[ty + j*8][tx] = W_in[(size_t)(k0 + ty + j*8) * 4096 + n0 + tx];
        __syncthreads();
#pragma unroll
        for (int j = 0; j < 4; ++j)
            WinT[(size_t)(n0 + ty + j*8) * 1024 + k0 + tx] = f2bf(tile[tx][ty + j*8]);
    } else if (bid < PREP_A + PREP_B + PREP_C) {
        int b2 = bid - PREP_A - PREP_B;         // W_out: K=2048, N=1024
        int n0 = (b2 & 31) * 32, k0 = (b2 >> 5) * 32;
        int tx = tid & 31, ty = tid >> 5;
        float (*tile)[33] = (float (*)[33])smem;
        float* red1 = smem + 32 * 33;
        float* red2 = red1 + 8 * 32;
        float p1 = 0.f, p2 = 0.f;              // col sums for n = n0+tx
#pragma unroll
        for (int j = 0; j < 4; ++j) {
            int k = k0 + ty + j * 8;
            float w = W_out[(size_t)k * 1024 + n0 + tx];
            float lw = lnw[k], lb = lnb[k];
            tile[ty + j*8][tx] = lw * w;
            p1 += lw * w; p2 += lb * w;
        }
        __syncthreads();
#pragma unroll
        for (int j = 0; j < 4; ++j)
            W1T[(size_t)(n0 + ty + j*8) * 2048 + k0 + tx] = f2bf(tile[tx][ty + j*8]);
        red1[ty * 32 + tx] = p1; red2[ty * 32 + tx] = p2;
        __syncthreads();
        if (ty == 0) {
            float a = 0.f, b = 0.f;
#pragma unroll
            for (int t = 0; t < 8; ++t) { a += red1[t * 32 + tx]; b += red2[t * 32 + tx]; }
            atomicAdd(&s1[n0 + tx], a);
            atomicAdd(&c2[n0 + tx], b);
        }
    } else {
        int c = (bid - PREP_A - PREP_B - PREP_C) * 256 + tid;
        if (c < D_MODEL) {
            float nu = expf(-expf(nu_log[c]));
            float th = expf(theta_log[c]);
            fr[c] = nu * cosf(th);
            fi[c] = nu * sinf(th);
            gm[c] = expf(gamma_log[c]);
        }
    }
}

#define P_PRE  do { __builtin_amdgcn_sched_barrier(0); __builtin_amdgcn_s_barrier();  \
                    asm volatile("s_waitcnt lgkmcnt(0)" ::: "memory");                \
                    __builtin_amdgcn_sched_barrier(0);                                \
                    __builtin_amdgcn_s_setprio(1); } while (0)
#define P_POST do { __builtin_amdgcn_s_setprio(0); __builtin_amdgcn_sched_barrier(0); \
                    __builtin_amdgcn_s_barrier();                                     \
                    __builtin_amdgcn_sched_barrier(0); } while (0)

// ------- GEMM1: 256x256-tile 8-phase bf16 MFMA (BK=64, counted vmcnt) ------
__global__ __launch_bounds__(512) void gemm256(
    const ushort* __restrict__ A, const ushort* __restrict__ B,
    int K, const float* __restrict__ bias,
    const float* __restrict__ gamma,
    ushort* __restrict__ out_r, ushort* __restrict__ out_i,
    ushort* __restrict__ out_o) {
    __shared__ ushort LA[2][256 * 64];   // 64 KiB
    __shared__ ushort LB[2][256 * 64];   // 64 KiB  (128 KiB total, 1 WG/CU)
    int tid = threadIdx.x;
    int lane = tid & 63;
    int wave = tid >> 6;
    int wp = wave >> 2;                  // 0..1
    int wq = wave & 3;                   // 0..3
    int lr = lane & 15, q = lane >> 4;
    int swl = lr & 7;
    int rs8 = tid >> 3, ch = tid & 7;    // staging: row-in-round, chunk
    int sw8 = (ch ^ (rs8 & 7)) * 8;      // pre-swizzled global k-offset

    int gx = gridDim.x;
    int nwg = gx * gridDim.y;
    int lid = blockIdx.y * gx + blockIdx.x;
    int per = nwg >> 3;
    int sid = (lid & 7) * per + (lid >> 3);
    long m0 = (long)(sid / gx) * 256;
    long n0 = (long)(sid % gx) * 256;
    const int NT = K >> 6;

    const ushort* Abase = A + (size_t)(m0 + rs8) * K + sw8;
    const ushort* Bbase = B + (size_t)(n0 + rs8) * K + sw8;

    floatx4 acc[8][4] = {};

#define STG_A(kt, P, R) GLOAD_LDS16(Abase + (size_t)(R) * K + (kt), \
                                    &LA[P][((R) + rs8) * 64 + ch * 8])
#define STG_B(kt, P, R) GLOAD_LDS16(Bbase + (size_t)(R) * K + (kt), \
                                    &LB[P][((R) + rs8) * 64 + ch * 8])

    // prologue: tile0 complete -> buf0; tile1 Ah0,Bh0,Bh1 -> buf1
    STG_A(0, 0, 0);    STG_A(0, 0, 64);
    STG_B(0, 0, 0);    STG_B(0, 0, 64);
    STG_B(0, 0, 128);  STG_B(0, 0, 192);
    STG_A(0, 0, 128);  STG_A(0, 0, 192);
    STG_A(64, 1, 0);   STG_A(64, 1, 64);
    STG_B(64, 1, 0);   STG_B(64, 1, 64);
    STG_B(64, 1, 128); STG_B(64, 1, 192);
    asm volatile("s_waitcnt vmcnt(6)" ::: "memory");
    __builtin_amdgcn_s_barrier();

    for (int t = 0; t < NT; ++t) {
        const int p = t & 1;
        int kt1 = (t + 1 < NT) ? (t + 1) << 6 : 0;
        int kt2 = (t + 2 < NT) ? (t + 2) << 6 : 0;
        short8 a[2][4], b0[2][2], b1[2][2];

        // ---- P1: quadrant (mh0,nh0); stage Ah1(t+1) -> buf p^1 ----
#pragma unroll
        for (int ks = 0; ks < 2; ++ks) {
#pragma unroll
            for (int r = 0; r < 4; ++r)
                a[ks][r] = *(const short8*)&LA[p][(wp * 64 + r * 16 + lr) * 64 + ((ks * 4 + q) ^ swl) * 8];
#pragma unroll
            for (int c = 0; c < 2; ++c)
                b0[ks][c] = *(const short8*)&LB[p][(wq * 32 + c * 16 + lr) * 64 + ((ks * 4 + q) ^ swl) * 8];
        }
        STG_A(kt1, p ^ 1, 128); STG_A(kt1, p ^ 1, 192);
        P_PRE;
#pragma unroll
        for (int ks = 0; ks < 2; ++ks)
#pragma unroll
            for (int r = 0; r < 4; ++r)
#pragma unroll
                for (int c = 0; c < 2; ++c)
                    acc[r][c] = __builtin_amdgcn_mfma_f32_16x16x32_bf16(
                        a[ks][r], b0[ks][c], acc[r][c], 0, 0, 0);
        P_POST;

        // ---- P2: quadrant (mh0,nh1); stage Ah0(t+2) -> buf p ----
#pragma unroll
        for (int ks = 0; ks < 2; ++ks)
#pragma unroll
            for (int c = 0; c < 2; ++c)
                b1[ks][c] = *(const short8*)&LB[p][(128 + wq * 32 + c * 16 + lr) * 64 + ((ks * 4 + q) ^ swl) * 8];
        STG_A(kt2, p, 0); STG_A(kt2, p, 64);
        P_PRE;
#pragma unroll
        for (int ks = 0; ks < 2; ++ks)
#pragma unroll
            for (int r = 0; r < 4; ++r)
#pragma unroll
                for (int c = 0; c < 2; ++c)
                    acc[r][2 + c] = __builtin_amdgcn_mfma_f32_16x16x32_bf16(
                        a[ks][r], b1[ks][c], acc[r][2 + c], 0, 0, 0);
        P_POST;

        // ---- P3: quadrant (mh1,nh0); stage Bh0(t+2) -> buf p ----
#pragma unroll
        for (int ks = 0; ks < 2; ++ks)
#pragma unroll
            for (int r = 0; r < 4; ++r)
                a[ks][r] = *(const short8*)&LA[p][(128 + wp * 64 + r * 16 + lr) * 64 + ((ks * 4 + q) ^ swl) * 8];
        STG_B(kt2, p, 0); STG_B(kt2, p, 64);
        P_PRE;
#pragma unroll
        for (int ks = 0; ks < 2; ++ks)
#pragma unroll
            for (int r = 0; r < 4; ++r)
#pragma unroll
                for (int c = 0; c < 2; ++c)
                    acc[4 + r][c] = __builtin_amdgcn_mfma_f32_16x16x32_bf16(
                        a[ks][r], b0[ks][c], acc[4 + r][c], 0, 0, 0);
        P_POST;

        // ---- P4: quadrant (mh1,nh1); stage Bh1(t+2) -> buf p; vmcnt(6) ----
        STG_B(kt2, p, 128); STG_B(kt2, p, 192);
        asm volatile("s_waitcnt vmcnt(6)" ::: "memory");
        P_PRE;
#pragma unroll
        for (int ks = 0; ks < 2; ++ks)
#pragma unroll
            for (int r = 0; r < 4; ++r)
#pragma unroll
                for (int c = 0; c < 2; ++c)
                    acc[4 + r][2 + c] = __builtin_amdgcn_mfma_f32_16x16x32_bf16(
                        a[ks][r], b1[ks][c], acc[4 + r][2 + c], 0, 0, 0);
        P_POST;
    }
    asm volatile("s_waitcnt vmcnt(0)" ::: "memory");

    int sector = (int)(n0 >> 10);                // block-uniform (BN=256)
    if (sector < 2) {
        ushort* dst = sector ? out_i : out_r;
#pragma unroll
        for (int nh = 0; nh < 2; ++nh)
#pragma unroll
            for (int c = 0; c < 2; ++c) {
                int lc = (int)(n0 & 1023) + nh * 128 + wq * 32 + c * 16 + lr;
                float bv = bias[(sector << 10) + lc];
                float gv = gamma[lc];
#pragma unroll
                for (int mh = 0; mh < 2; ++mh)
#pragma unroll
                    for (int r = 0; r < 4; ++r)
#pragma unroll
                        for (int g = 0; g < 4; ++g) {
                            long row = m0 + mh * 128 + wp * 64 + r * 16 + q * 4 + g;
                            dst[row * 1024 + lc] = f2bf(gv * (acc[mh * 4 + r][nh * 2 + c][g] + bv));
                        }
            }
    } else {
        int oc0 = (int)(n0 - 2048);
#pragma unroll
        for (int nh = 0; nh < 2; ++nh)
#pragma unroll
            for (int c = 0; c < 2; ++c) {
                int oc = oc0 + nh * 128 + wq * 32 + c * 16 + lr;
                float bv = bias[2048 + oc];
#pragma unroll
                for (int mh = 0; mh < 2; ++mh)
#pragma unroll
                    for (int r = 0; r < 4; ++r)
#pragma unroll
                        for (int g = 0; g < 4; ++g) {
                            long row = m0 + mh * 128 + wp * 64 + r * 16 + q * 4 + g;
                            out_o[row * 2048 + oc] = f2bf(acc[mh * 4 + r][nh * 2 + c][g] + bv);
                        }
            }
    }
#undef STG_A
#undef STG_B
}

// ------- GEMM2: 128x256-tile 8-phase (BK=64, counted vmcnt(3)) -------------
// R4-verified kernel, unchanged.
__global__ __launch_bounds__(512) void gemm2_8ph(
    const ushort* __restrict__ A, const ushort* __restrict__ B,
    int K, int N, const float* __restrict__ bias, float* __restrict__ outC,
    const float* __restrict__ mu, const float* __restrict__ rs,
    const float* __restrict__ s1, const float* __restrict__ c2) {
    __shared__ ushort LA[2][128 * 64];   // 32 KiB
    __shared__ ushort LB[2][256 * 64];   // 64 KiB  (96 KiB total, 1 WG/CU)
    int tid = threadIdx.x;
    int lane = tid & 63;
    int wave = tid >> 6;
    int wp = wave >> 2;                  // 0..1 (M)
    int wq = wave & 3;                   // 0..3 (N)
    int lr = lane & 15, q = lane >> 4;
    int swl = lr & 7;
    int rs8 = tid >> 3, ch = tid & 7;
    int sw8 = (ch ^ (rs8 & 7)) * 8;

    int gx = gridDim.x;                  // 4
    int nwg = gx * gridDim.y;            // 256
    int lid = blockIdx.y * gx + blockIdx.x;
    int per = nwg >> 3;
    int sid = (lid & 7) * per + (lid >> 3);
    long m0 = (long)(sid / gx) * 128;
    long n0 = (long)(sid % gx) * 256;
    const int NT = K >> 6;

    const ushort* Abase = A + (size_t)(m0 + rs8) * K + sw8;
    const ushort* Bbase = B + (size_t)(n0 + rs8) * K + sw8;

    floatx4 acc[4][4] = {};              // [mh*2+r][nh*2+c]

#define STG2_A(kt, P, R) GLOAD_LDS16(Abase + (size_t)(R) * K + (kt), \
                                     &LA[P][((R) + rs8) * 64 + ch * 8])
#define STG2_B(kt, P, R) GLOAD_LDS16(Bbase + (size_t)(R) * K + (kt), \
                                     &LB[P][((R) + rs8) * 64 + ch * 8])

    // prologue: tile0 full (6 loads) -> buf0; tile1 Ah0 + Bh0 -> buf1
    STG2_A(0, 0, 0);   STG2_A(0, 0, 64);
    STG2_B(0, 0, 0);   STG2_B(0, 0, 64);
    STG2_B(0, 0, 128); STG2_B(0, 0, 192);
    STG2_A(64, 1, 0);
    STG2_B(64, 1, 0);  STG2_B(64, 1, 64);
    asm volatile("s_waitcnt vmcnt(3)" ::: "memory");
    __builtin_amdgcn_s_barrier();

    for (int t = 0; t < NT; ++t) {
        const int p = t & 1;
        int kt1 = (t + 1 < NT) ? (t + 1) << 6 : 0;
        int kt2 = (t + 2 < NT) ? (t + 2) << 6 : 0;
        short8 a[2][2], b0[2][2], b1[2][2];

        // ---- P1 (mh0,nh0): read a(mh0) + b0; stage Ah1(t+1), Bh1(t+1) ----
#pragma unroll
        for (int ks = 0; ks < 2; ++ks) {
#pragma unroll
            for (int r = 0; r < 2; ++r)
                a[ks][r] = *(const short8*)&LA[p][(wp * 32 + r * 16 + lr) * 64 + ((ks * 4 + q) ^ swl) * 8];
#pragma unroll
            for (int c = 0; c < 2; ++c)
                b0[ks][c] = *(const short8*)&LB[p][(wq * 32 + c * 16 + lr) * 64 + ((ks * 4 + q) ^ swl) * 8];
        }
        STG2_A(kt1, p ^ 1, 64);
        STG2_B(kt1, p ^ 1, 128); STG2_B(kt1, p ^ 1, 192);
        P_PRE;
#pragma unroll
        for (int ks = 0; ks < 2; ++ks)
#pragma unroll
            for (int r = 0; r < 2; ++r)
#pragma unroll
                for (int c = 0; c < 2; ++c)
                    acc[r][c] = __builtin_amdgcn_mfma_f32_16x16x32_bf16(
                        a[ks][r], b0[ks][c], acc[r][c], 0, 0, 0);
        P_POST;

        // ---- P2 (mh0,nh1): read b1 ----
#pragma unroll
        for (int ks = 0; ks < 2; ++ks)
#pragma unroll
            for (int c = 0; c < 2; ++c)
                b1[ks][c] = *(const short8*)&LB[p][(128 + wq * 32 + c * 16 + lr) * 64 + ((ks * 4 + q) ^ swl) * 8];
        P_PRE;
#pragma unroll
        for (int ks = 0; ks < 2; ++ks)
#pragma unroll
            for (int r = 0; r < 2; ++r)
#pragma unroll
                for (int c = 0; c < 2; ++c)
                    acc[r][2 + c] = __builtin_amdgcn_mfma_f32_16x16x32_bf16(
                        a[ks][r], b1[ks][c], acc[r][2 + c], 0, 0, 0);
        P_POST;

        // ---- P3 (mh1,nh0): read a(mh1); stage Ah0(t+2) -> buf p ----
#pragma unroll
        for (int ks = 0; ks < 2; ++ks)
#pragma unroll
            for (int r = 0; r < 2; ++r)
                a[ks][r] = *(const short8*)&LA[p][(64 + wp * 32 + r * 16 + lr) * 64 + ((ks * 4 + q) ^ swl) * 8];
        STG2_A(kt2, p, 0);
        P_PRE;
#pragma unroll
        for (int ks = 0; ks < 2; ++ks)
#pragma unroll
            for (int r = 0; r < 2; ++r)
#pragma unroll
                for (int c = 0; c < 2; ++c)
                    acc[2 + r][c] = __builtin_amdgcn_mfma_f32_16x16x32_bf16(
                        a[ks][r], b0[ks][c], acc[2 + r][c], 0, 0, 0);
        P_POST;

        // ---- P4 (mh1,nh1): stage Bh0(t+2) -> buf p; vmcnt(3) ----
        STG2_B(kt2, p, 0); STG2_B(kt2, p, 64);
        asm volatile("s_waitcnt vmcnt(3)" ::: "memory");
        P_PRE;
#pragma unroll
        for (int ks = 0; ks < 2; ++ks)
#pragma unroll
            for (int r = 0; r < 2; ++r)
#pragma unroll
                for (int c = 0; c < 2; ++c)
                    acc[2 + r][2 + c] = __builtin_amdgcn_mfma_f32_16x16x32_bf16(
                        a[ks][r], b1[ks][c], acc[2 + r][2 + c], 0, 0, 0);
        P_POST;
    }
    asm volatile("s_waitcnt vmcnt(0)" ::: "memory");

    // LN-folded epilogue
#pragma unroll
    for (int nh = 0; nh < 2; ++nh)
#pragma unroll
        for (int c = 0; c < 2; ++c) {
            long col = n0 + nh * 128 + wq * 32 + c * 16 + lr;
            float bc = c2[col] + bias[col];
            float s1c = s1[col];
#pragma unroll
            for (int mh = 0; mh < 2; ++mh)
#pragma unroll
                for (int r = 0; r < 2; ++r)
#pragma unroll
                    for (int g = 0; g < 4; ++g) {
                        long row = m0 + mh * 64 + wp * 32 + r * 16 + q * 4 + g;
                        outC[row * (long)N + col] =
                            rs[row] * (acc[mh * 2 + r][nh * 2 + c][g] - mu[row] * s1c) + bc;
                    }
        }
#undef STG2_A
#undef STG2_B
}

// ---------------- chunked complex scan: 2 channels/thread, uint loads ------
// pass A: local scan per chunk, emit chunk-FINAL state as float4.
__global__ __launch_bounds__(256) void scan_carries(
    const ushort* __restrict__ in_r, const ushort* __restrict__ in_i,
    float* __restrict__ carry,
    const float* __restrict__ fr_, const float* __restrict__ fi_) {
    int t = blockIdx.x * 256 + threadIdx.x;  // BB*512*NCHUNK = 131072
    int cp = t & 511;
    int ck = (t >> 9) & (NCHUNK - 1);
    int b = t >> 15;
    int c0 = cp * 2;
    float f0r = fr_[c0], f0i = fi_[c0], f1r = fr_[c0 + 1], f1i = fi_[c0 + 1];
    size_t base = ((size_t)(b * TT + ck * CHLEN)) * 1024 + c0;
    float h0r = 0.f, h0i = 0.f, h1r = 0.f, h1i = 0.f;
#pragma unroll 8
    for (int j = 0; j < CHLEN; ++j) {
        uint ur = *(const uint*)(in_r + base + (size_t)j * 1024);
        uint ui = *(const uint*)(in_i + base + (size_t)j * 1024);
        float r0 = bf2f((ushort)ur), r1 = bf2f((ushort)(ur >> 16));
        float i0 = bf2f((ushort)ui), i1 = bf2f((ushort)(ui >> 16));
        float n0r = f0r * h0r - f0i * h0i + r0;
        float n0i = f0r * h0i + f0i * h0r + i0;
        float n1r = f1r * h1r - f1i * h1i + r1;
        float n1i = f1r * h1i + f1i * h1r + i1;
        h0r = n0r; h0i = n0i; h1r = n1r; h1i = n1i;
    }
    ((float4*)carry)[((size_t)b * NCHUNK + ck) * 512 + cp] =
        make_float4(h0r, h0i, h1r, h1i);
}

// middle: sequential prefix over NCHUNK carries, converts to carry-INs.
__global__ __launch_bounds__(256) void carry_prefix(
    float* __restrict__ carry,
    const float* __restrict__ fr_, const float* __restrict__ fi_) {
    int t = blockIdx.x * 256 + threadIdx.x;   // BB*512 = 2048
    int cp = t & 511, b = t >> 9;
    int c0 = cp * 2;
    float a0r = fr_[c0], a0i = fi_[c0], a1r = fr_[c0 + 1], a1i = fi_[c0 + 1];
#pragma unroll
    for (int s = 0; s < 5; ++s) {            // f^32 (CHLEN=32=2^5)
        float t0r = a0r * a0r - a0i * a0i, t0i = 2.f * a0r * a0i;
        float t1r = a1r * a1r - a1i * a1i, t1i = 2.f * a1r * a1i;
        a0r = t0r; a0i = t0i; a1r = t1r; a1i = t1i;
    }
    float4* base = (float4*)carry + (size_t)b * NCHUNK * 512 + cp;
    float C0r = 0.f, C0i = 0.f, C1r = 0.f, C1i = 0.f;
    for (int k = 0; k < NCHUNK; ++k) {
        float4 s = base[(size_t)k * 512];
        base[(size_t)k * 512] = make_float4(C0r, C0i, C1r, C1i);
        float n0r = a0r * C0r - a0i * C0i + s.x;
        float n0i = a0r * C0i + a0i * C0r + s.y;
        float n1r = a1r * C1r - a1i * C1i + s.z;
        float n1i = a1r * C1i + a1i * C1r + s.w;
        C0r = n0r; C0i = n0i; C1r = n1r; C1i = n1i;
    }
}

// pass B: load carry-in, rescan chunk, emit y' = h*silu(o).
__global__ __launch_bounds__(256) void scan_apply(
    const ushort* __restrict__ in_r, const ushort* __restrict__ in_i,
    const float* __restrict__ carry,
    const float* __restrict__ fr_, const float* __restrict__ fi_,
    const ushort* __restrict__ o, ushort* __restrict__ yb) {
    int t = blockIdx.x * 256 + threadIdx.x;  // 131072
    int cp = t & 511;
    int ck = (t >> 9) & (NCHUNK - 1);
    int b = t >> 15;
    int c0 = cp * 2;
    float f0r = fr_[c0], f0i = fi_[c0], f1r = fr_[c0 + 1], f1i = fi_[c0 + 1];
    float4 C = ((const float4*)carry)[((size_t)b * NCHUNK + ck) * 512 + cp];
    float h0r = C.x, h0i = C.y, h1r = C.z, h1i = C.w;
    size_t base = ((size_t)(b * TT + ck * CHLEN)) * 1024 + c0;
    size_t rowbase = (size_t)(b * TT + ck * CHLEN);
#pragma unroll 4
    for (int j = 0; j < CHLEN; ++j) {
        uint ur = *(const uint*)(in_r + base + (size_t)j * 1024);
        uint ui = *(const uint*)(in_i + base + (size_t)j * 1024);
        size_t ob = (rowbase + j) * 2048 + c0;
        uint uo1 = *(const uint*)(o + ob);
        uint uo2 = *(const uint*)(o + ob + 1024);
        float r0 = bf2f((ushort)ur), r1 = bf2f((ushort)(ur >> 16));
        float i0 = bf2f((ushort)ui), i1 = bf2f((ushort)(ui >> 16));
        float n0r = f0r * h0r - f0i * h0i + r0;
        float n0i = f0r * h0i + f0i * h0r + i0;
        float n1r = f1r * h1r - f1i * h1i + r1;
        float n1i = f1r * h1i + f1i * h1r + i1;
        h0r = n0r; h0i = n0i; h1r = n1r; h1i = n1i;
        float o00 = bf2f((ushort)uo1), o01 = bf2f((ushort)(uo1 >> 16));
        float o10 = bf2f((ushort)uo2), o11 = bf2f((ushort)(uo2 >> 16));
        float y00 = h0r * o00 / (1.f + __expf(-o00));
        float y01 = h1r * o01 / (1.f + __expf(-o01));
        float y10 = h0i * o10 / (1.f + __expf(-o10));
        float y11 = h1i * o11 / (1.f + __expf(-o11));
        *(uint*)(yb + ob) = (uint)f2bf(y00) | ((uint)f2bf(y01) << 16);
        *(uint*)(yb + ob + 1024) = (uint)f2bf(y10) | ((uint)f2bf(y11) << 16);
    }
}

// ---------------- per-row stats of y': one WAVE per row (R9-verified) ------
__global__ __launch_bounds__(256) void row_stats(
    const ushort* __restrict__ yb, float* __restrict__ mu_o,
    float* __restrict__ rs_o) {
    int tid = threadIdx.x;
    long row = (long)blockIdx.x * 4 + (tid >> 6);
    int lane = tid & 63;
    const ushort* p = yb + row * 2048 + lane * 32;
    float s = 0.f, s2 = 0.f;
#pragma unroll
    for (int j = 0; j < 4; ++j) {
        uint4 raw = *(const uint4*)(p + j * 8);
        unsigned w[4] = {raw.x, raw.y, raw.z, raw.w};
#pragma unroll
        for (int e = 0; e < 4; ++e) {
            float a = bf2f((ushort)(w[e] & 0xffff));
            float bq = bf2f((ushort)(w[e] >> 16));
            s += a + bq; s2 += a * a + bq * bq;
        }
    }
#pragma unroll
    for (int off = 32; off > 0; off >>= 1) {
        s += __shfl_down(s, off, 64);
        s2 += __shfl_down(s2, off, 64);
    }
    if (lane == 0) {
        float mu = s * (1.f / 2048.f);
        float var = s2 * (1.f / 2048.f) - mu * mu;
        mu_o[row] = mu;
        rs_o[row] = rsqrtf(var + 1e-5f);
    }
}

// ---------------- launch ----------------

extern "C" void kernel_launch(void* const* d_in, const int* in_sizes, int n_in,
                              void* d_out, int out_size, void* d_ws, size_t ws_size,
                              hipStream_t stream) {
    const float* x         = (const float*)d_in[0];
    const float* W_in      = (const float*)d_in[1];
    const float* b_in      = (const float*)d_in[2];
    const float* nu_log    = (const float*)d_in[3];
    const float* theta_log = (const float*)d_in[4];
    const float* gamma_log = (const float*)d_in[5];
    const float* ln_w      = (const float*)d_in[6];
    const float* ln_b      = (const float*)d_in[7];
    const float* W_out     = (const float*)d_in[8];
    const float* b_out     = (const float*)d_in[9];
    float* out = (float*)d_out;

    char* ws = (char*)d_ws;
    size_t off = 0;
    auto alloc = [&](size_t bytes) {
        char* p = ws + off;
        off += (bytes + 255) & ~(size_t)255;
        return p;
    };
    ushort* xb    = (ushort*)alloc((size_t)ROWS * 1024 * 2);
    ushort* WinT  = (ushort*)alloc((size_t)4096 * 1024 * 2);
    ushort* W1T   = (ushort*)alloc((size_t)1024 * 2048 * 2);
    float*  fr    = (float*)alloc(1024 * 4);
    float*  fi    = (float*)alloc(1024 * 4);
    float*  gm    = (float*)alloc(1024 * 4);
    float*  s1c2  = (float*)alloc(2048 * 4);           // s1 | c2
    float*  s1    = s1c2;
    float*  c2    = s1c2 + 1024;
    ushort* in_r  = (ushort*)alloc((size_t)ROWS * 1024 * 2);
    ushort* in_i  = (ushort*)alloc((size_t)ROWS * 1024 * 2);
    ushort* obuf  = (ushort*)alloc((size_t)ROWS * 2048 * 2);
    float*  carry = (float*)alloc((size_t)BB * 1024 * NCHUNK * 2 * 4);
    ushort* yb    = (ushort*)alloc((size_t)ROWS * 2048 * 2);
    float*  muv   = (float*)alloc(ROWS * 4);
    float*  rsv   = (float*)alloc(ROWS * 4);

    hipMemsetAsync(s1c2, 0, 2048 * 4, stream);

    prep_all<<<PREP_A + PREP_B + PREP_C + 4, 256, 0, stream>>>(
        x, xb, W_in, WinT, W_out, W1T, ln_w, ln_b, s1, c2,
        nu_log, theta_log, gamma_log, fr, fi, gm);

    gemm256<<<dim3(4096 / 256, ROWS / 256), 512, 0, stream>>>(
        xb, WinT, 1024, b_in, gm, in_r, in_i, obuf);

    scan_carries<<<BB * 512 * NCHUNK / 256, 256, 0, stream>>>(in_r, in_i, carry, fr, fi);
    carry_prefix<<<BB * 512 / 256, 256, 0, stream>>>(carry, fr, fi);
    scan_apply<<<BB * 512 * NCHUNK / 256, 256, 0, stream>>>(
        in_r, in_i, carry, fr, fi, obuf, yb);

    row_stats<<<ROWS / 4, 256, 0, stream>>>(yb, muv, rsv);

    gemm2_8ph<<<dim3(1024 / 256, ROWS / 128), 512, 0, stream>>>(
        yb, W1T, 2048, 1024, b_out, out, muv, rsv, s1, c2);
}